// Round 23
// baseline (66.163 us; speedup 1.0000x reference)
//
#include <hip/hip_runtime.h>
#include <hip/hip_bf16.h>
#include <cmath>

#define DD   10
#define FF   32
#define PPW  6                  // pairs per wave (60 rows + 4 shadow slots)
#define NW   4                  // waves per block
#define NT   (NW * 64)
#define RPW  (PPW * DD)         // 60 real rows per wave
#define OSTR 36                 // out LDS row stride in floats (144 B)

typedef float f32x4  __attribute__((ext_vector_type(4)));
typedef short bf16x8 __attribute__((ext_vector_type(8)));
typedef short s16x4  __attribute__((ext_vector_type(4)));

// Kernel 1: summed[b,v,f] = sum_d inputs[b,v,d,f]  — at its roofline
__global__ __launch_bounds__(256) void sum_d4_kernel(
    const f32x4* __restrict__ in, f32x4* __restrict__ out, int n4) {
    int idx = blockIdx.x * 256 + threadIdx.x;
    if (idx >= n4) return;
    int f4 = idx & 7;
    int bv = idx >> 3;
    const f32x4* p = in + (size_t)bv * (DD * 8) + f4;
    f32x4 s = __builtin_nontemporal_load(p);
#pragma unroll
    for (int d = 1; d < DD; ++d) s += __builtin_nontemporal_load(p + d * 8);
    out[idx] = s;
}

__device__ __forceinline__ float dpp_ror_add(float v, const int sel) {
    int x;
    switch (sel) {
        case 1:  x = __builtin_amdgcn_update_dpp(0, __float_as_int(v), 0x121, 0xF, 0xF, true); break;
        case 2:  x = __builtin_amdgcn_update_dpp(0, __float_as_int(v), 0x122, 0xF, 0xF, true); break;
        case 4:  x = __builtin_amdgcn_update_dpp(0, __float_as_int(v), 0x124, 0xF, 0xF, true); break;
        default: x = __builtin_amdgcn_update_dpp(0, __float_as_int(v), 0x128, 0xF, 0xF, true); break;
    }
    return v + __int_as_float(x);
}

__device__ __forceinline__ short f2bf(float x) {
    __hip_bfloat16 h = __float2bfloat16(x);
    return *reinterpret_cast<short*>(&h);
}

// Kernel 2 (R22 + asm-forced 16-deep staging): descriptor+bpermute -> ONE asm
//   block with 16 global_load_dwordx4 in flight -> bf16 A in LDS -> MFMA ->
//   inline aw -> softmax -> LDS out-buffer -> coalesced plain b128 stores.
__global__ __launch_bounds__(NT, 4) void gat_kernel(   // VGPR cap 128 == LDS occ ceiling
    const float* __restrict__ summed,
    const float* __restrict__ init,
    const float* __restrict__ mask,
    const float* __restrict__ Wk,
    const float* __restrict__ Wb,
    const float* __restrict__ Ak,
    const int* __restrict__ adj,
    const int* __restrict__ mask_index_p,
    float* __restrict__ out,
    int B, int V) {
    __shared__ __align__(16) char sBuf[NW][64 * OSTR * 4];
    __shared__ float sAW[NW][64];

    const int t    = threadIdx.x;
    const int lane = t & 63;
    const int w    = t >> 6;
    const int l8   = lane & 7;          // 16B chunk within row (staging)
    const int r8   = lane >> 3;         // row within 8-row staging group
    const int col  = lane & 15;         // MFMA col
    const int q    = lane >> 4;         // MFMA k-/row-quadrant
    const int BV   = B * V;
    const int NR   = BV * DD;
    const int mask_index = *mask_index_p;

    short* sA   = (short*)&sBuf[w][0];  // row stride 40 shorts (80 B)
    float* sOut = (float*)&sBuf[w][0];  // row stride 36 floats (144 B)

    const int wp0 = (blockIdx.x * NW + w) * PPW;
    const int tr0 = wp0 * DD;

    // ---- descriptor per slot-lane: (gather-row << 7) | zm0bit(2) | maskbit(1) ----
    int sr = tr0 + lane;
    if (sr >= NR) sr = NR - 1;
    const int   a_s = adj[sr];
    const float m_s = mask[sr];
    int ac = a_s < 0 ? 0 : (a_s >= V ? V - 1 : a_s);        // JAX clamp
    int bv_s = sr / DD;
    int b_s  = (bv_s >= 2 * V) ? ((bv_s >= 3 * V) ? 3 : 2) : ((bv_s >= V) ? 1 : 0);
    const int gidx = ((b_s * V + ac) << 7) | ((m_s != 0.f) ? 2 : 0)
                   | ((a_s == mask_index) ? 1 : 0);

    // ---- staging: 8 bpermute descriptors, then 16 loads forced in flight ----
    const char* sb = (const char*)summed;
    int gp[8];
#pragma unroll
    for (int i = 0; i < 8; ++i)
        gp[i] = __builtin_amdgcn_ds_bpermute((8 * i + r8) << 2, gidx);

    const f32x4* ga[8];
    const f32x4* ia[8];
#pragma unroll
    for (int i = 0; i < 8; ++i) {
        int rr = tr0 + 8 * i + r8;
        if (rr >= NR) rr = NR - 1;
        ia[i] = (const f32x4*)(init + (size_t)rr * FF) + l8;
        ga[i] = (const f32x4*)(sb + ((uint32_t)gp[i] & ~127u) + (l8 << 4));
    }

    f32x4 iv[8], gv[8];
    asm volatile(
        "global_load_dwordx4 %[i0], %[A0], off\n\t"
        "global_load_dwordx4 %[g0], %[B0], off\n\t"
        "global_load_dwordx4 %[i1], %[A1], off\n\t"
        "global_load_dwordx4 %[g1], %[B1], off\n\t"
        "global_load_dwordx4 %[i2], %[A2], off\n\t"
        "global_load_dwordx4 %[g2], %[B2], off\n\t"
        "global_load_dwordx4 %[i3], %[A3], off\n\t"
        "global_load_dwordx4 %[g3], %[B3], off\n\t"
        "global_load_dwordx4 %[i4], %[A4], off\n\t"
        "global_load_dwordx4 %[g4], %[B4], off\n\t"
        "global_load_dwordx4 %[i5], %[A5], off\n\t"
        "global_load_dwordx4 %[g5], %[B5], off\n\t"
        "global_load_dwordx4 %[i6], %[A6], off\n\t"
        "global_load_dwordx4 %[g6], %[B6], off\n\t"
        "global_load_dwordx4 %[i7], %[A7], off\n\t"
        "global_load_dwordx4 %[g7], %[B7], off\n\t"
        "s_waitcnt vmcnt(0)"
        : [i0]"=&v"(iv[0]), [i1]"=&v"(iv[1]), [i2]"=&v"(iv[2]), [i3]"=&v"(iv[3]),
          [i4]"=&v"(iv[4]), [i5]"=&v"(iv[5]), [i6]"=&v"(iv[6]), [i7]"=&v"(iv[7]),
          [g0]"=&v"(gv[0]), [g1]"=&v"(gv[1]), [g2]"=&v"(gv[2]), [g3]"=&v"(gv[3]),
          [g4]"=&v"(gv[4]), [g5]"=&v"(gv[5]), [g6]"=&v"(gv[6]), [g7]"=&v"(gv[7])
        : [A0]"v"(ia[0]), [A1]"v"(ia[1]), [A2]"v"(ia[2]), [A3]"v"(ia[3]),
          [A4]"v"(ia[4]), [A5]"v"(ia[5]), [A6]"v"(ia[6]), [A7]"v"(ia[7]),
          [B0]"v"(ga[0]), [B1]"v"(ga[1]), [B2]"v"(ga[2]), [B3]"v"(ga[3]),
          [B4]"v"(ga[4]), [B5]"v"(ga[5]), [B6]"v"(ga[6]), [B7]"v"(ga[7])
        : "memory");

#pragma unroll
    for (int i = 0; i < 8; ++i) {
        int slot = 8 * i + r8;               // covers all 64 slots
        f32x4 v = iv[i];
        if (!(gp[i] & 1)) v += gv[i];
        if (gp[i] & 2) v = (f32x4){0.f, 0.f, 0.f, 0.f};
        s16x4 h;
        h[0] = f2bf(v.x); h[1] = f2bf(v.y); h[2] = f2bf(v.z); h[3] = f2bf(v.w);
        *(s16x4*)(sA + slot * 40 + l8 * 4) = h;
    }

    // ---- B-frag (W), bias, a: loaded after staging ----
    bf16x8 bw0, bw1;
#pragma unroll
    for (int j = 0; j < 8; ++j) {
        int k = q * 8 + j;
        bw0[j] = f2bf(Wk[k * FF + col]);
        bw1[j] = f2bf(Wk[k * FF + col + 16]);
    }
    const float bias0 = Wb[col], bias1 = Wb[col + 16];
    const float ak0   = Ak[col], ak1   = Ak[col + 16];

    // ---- A-frags + 8 MFMA (W shared in-register across the wave) ----
    const f32x4 zz = {0.f, 0.f, 0.f, 0.f};
    f32x4 acc0[4], acc1[4];
#pragma unroll
    for (int g4 = 0; g4 < 4; ++g4) {
        bf16x8 af = *(const bf16x8*)(sA + (g4 * 16 + col) * 40 + q * 8);
        acc0[g4] = __builtin_amdgcn_mfma_f32_16x16x32_bf16(af, bw0, zz, 0, 0, 0);
        acc1[g4] = __builtin_amdgcn_mfma_f32_16x16x32_bf16(af, bw1, zz, 0, 0, 0);
    }

    // ---- epilogue: relu/bias/zm, attn dot, aw -> sAW inline (no live buffer) ----
#pragma unroll
    for (int g4 = 0; g4 < 4; ++g4) {
#pragma unroll
        for (int reg = 0; reg < 4; ++reg) {
            const int row = g4 * 16 + q * 4 + reg;
            const int fl  = __builtin_amdgcn_ds_bpermute(row << 2, gidx);
            const float zm = (fl & 2) ? 0.f : 1.f;
            float t0 = fmaxf(acc0[g4][reg] + bias0, 0.f) * zm;
            float t1 = fmaxf(acc1[g4][reg] + bias1, 0.f) * zm;
            acc0[g4][reg] = t0;
            acc1[g4][reg] = t1;
            float p = fmaf(t0, ak0, t1 * ak1);
            p = dpp_ror_add(p, 1);
            p = dpp_ror_add(p, 2);
            p = dpp_ror_add(p, 4);
            p = dpp_ror_add(p, 8);           // all 16 lanes hold the row sum
            const float aw = p - 1e7f * (1.f - zm);
            if ((lane & 15) == reg)          // one writer per 16-group
                sAW[w][row] = aw;            // live range ends here -> no spill
        }
    }

    // ---- softmax over the pair's 10 rows (slot = lane) ----
    int p_raw = lane / DD;
    const int pe = (p_raw < PPW) ? p_raw : (PPW - 1);
    const int base = pe * DD;
    float mx = -INFINITY;
    float av[DD];
#pragma unroll
    for (int d = 0; d < DD; ++d) { av[d] = sAW[w][base + d]; mx = fmaxf(mx, av[d]); }
    float den = 0.f;
#pragma unroll
    for (int d = 0; d < DD; ++d) den += __expf(av[d] - mx);
    const float coef = __expf(sAW[w][lane] - mx) / den;   // this slot's coefficient

    // ---- coef*T -> sOut (aliases sA; ordering via acc register dependence) ----
#pragma unroll
    for (int g4 = 0; g4 < 4; ++g4) {
#pragma unroll
        for (int reg = 0; reg < 4; ++reg) {
            const int row = g4 * 16 + q * 4 + reg;
            const float cr = __int_as_float(
                __builtin_amdgcn_ds_bpermute(row << 2, __float_as_int(coef)));
            float* op = sOut + row * OSTR + col;
            op[0]  = cr * acc0[g4][reg];
            op[16] = cr * acc1[g4][reg];     // -> ds_write2_b32
        }
    }

    // ---- coalesced epilogue: plain b128 stores (L2 absorbs) ----
    int nrows = NR - tr0;
    if (nrows < 0) nrows = 0;
    if (nrows > RPW) nrows = RPW;
    const int lim4 = nrows * 8;
    f32x4* ob = (f32x4*)(out + (size_t)tr0 * FF);
#pragma unroll
    for (int k = 0; k < 8; ++k) {
        int m = lane + (k << 6);
        if (m < lim4) {
            const f32x4 v = *(const f32x4*)(sOut + (m >> 3) * OSTR + ((m & 7) << 2));
            ob[m] = v;
        }
    }
}

extern "C" void kernel_launch(void* const* d_in, const int* in_sizes, int n_in,
                              void* d_out, int out_size, void* d_ws, size_t ws_size,
                              hipStream_t stream) {
    const float* inputs = (const float*)d_in[0];
    const float* init   = (const float*)d_in[1];
    const float* mask   = (const float*)d_in[2];
    const float* Wk     = (const float*)d_in[3];
    const float* Wb     = (const float*)d_in[4];
    const float* Ak     = (const float*)d_in[5];
    const int*   adj    = (const int*)d_in[6];
    const int*   mip    = (const int*)d_in[7];

    const int B   = 4;
    const int BVD = in_sizes[2];          // B*V*D
    const int V   = BVD / (B * DD);
    const int BV  = B * V;

    float* summed = (float*)d_ws;         // B*V*FF floats = 10.24 MB
    int n4 = BV * (FF / 4);
    hipLaunchKernelGGL(sum_d4_kernel, dim3((n4 + 255) / 256), dim3(256), 0, stream,
                       (const f32x4*)inputs, (f32x4*)summed, n4);
    const int ppb = NW * PPW;             // 24 pairs per block
    hipLaunchKernelGGL(gat_kernel, dim3((BV + ppb - 1) / ppb), dim3(NT), 0, stream,
                       summed, init, mask, Wk, Wb, Ak, adj, mip, (float*)d_out, B, V);
}

// Round 24
// 64.318 us; speedup vs baseline: 1.0287x; 1.0287x over previous
//
#include <hip/hip_runtime.h>
#include <hip/hip_bf16.h>
#include <cmath>

#define DD   10
#define FF   32
#define PPW  3                  // pairs per wave (30 rows + 2 shadow slots)
#define NSL  32                 // slots per wave (2 MFMA row-groups)
#define NW   4                  // waves per block
#define NT   (NW * 64)
#define RPW  (PPW * DD)         // 30 real rows per wave
#define OSTR 36                 // out LDS row stride in floats (144 B)

typedef float f32x4  __attribute__((ext_vector_type(4)));
typedef short bf16x8 __attribute__((ext_vector_type(8)));
typedef short s16x4  __attribute__((ext_vector_type(4)));

// Kernel 1: summed[b,v,f] = sum_d inputs[b,v,d,f]  — at its roofline
__global__ __launch_bounds__(256) void sum_d4_kernel(
    const f32x4* __restrict__ in, f32x4* __restrict__ out, int n4) {
    int idx = blockIdx.x * 256 + threadIdx.x;
    if (idx >= n4) return;
    int f4 = idx & 7;
    int bv = idx >> 3;
    const f32x4* p = in + (size_t)bv * (DD * 8) + f4;
    f32x4 s = __builtin_nontemporal_load(p);
#pragma unroll
    for (int d = 1; d < DD; ++d) s += __builtin_nontemporal_load(p + d * 8);
    out[idx] = s;
}

__device__ __forceinline__ float dpp_ror_add(float v, const int sel) {
    int x;
    switch (sel) {
        case 1:  x = __builtin_amdgcn_update_dpp(0, __float_as_int(v), 0x121, 0xF, 0xF, true); break;
        case 2:  x = __builtin_amdgcn_update_dpp(0, __float_as_int(v), 0x122, 0xF, 0xF, true); break;
        case 4:  x = __builtin_amdgcn_update_dpp(0, __float_as_int(v), 0x124, 0xF, 0xF, true); break;
        default: x = __builtin_amdgcn_update_dpp(0, __float_as_int(v), 0x128, 0xF, 0xF, true); break;
    }
    return v + __int_as_float(x);
}

__device__ __forceinline__ short f2bf(float x) {
    __hip_bfloat16 h = __float2bfloat16(x);
    return *reinterpret_cast<short*>(&h);
}

// Kernel 2 (R22 structure, half-size tile): 32 slots/wave -> 4.7 KB LDS/wave ->
//   32-wave/CU ceiling (HW max). Staging -> bf16 A -> 4 MFMA -> inline aw ->
//   softmax -> LDS out-buffer -> coalesced plain b128 stores.
__global__ __launch_bounds__(NT) void gat_kernel(
    const float* __restrict__ summed,
    const float* __restrict__ init,
    const float* __restrict__ mask,
    const float* __restrict__ Wk,
    const float* __restrict__ Wb,
    const float* __restrict__ Ak,
    const int* __restrict__ adj,
    const int* __restrict__ mask_index_p,
    float* __restrict__ out,
    int B, int V) {
    // sA (32 x 40 shorts = 2560 B) and sOut (32 x 36 floats = 4608 B) alias.
    __shared__ __align__(16) char sBuf[NW][NSL * OSTR * 4];   // 18432 B
    __shared__ float sAW[NW][NSL];

    const int t    = threadIdx.x;
    const int lane = t & 63;
    const int w    = t >> 6;
    const int l8   = lane & 7;          // 16B chunk within row (staging)
    const int r8   = lane >> 3;         // row within 8-row staging group
    const int col  = lane & 15;         // MFMA col
    const int q    = lane >> 4;         // MFMA k-/row-quadrant
    const int BV   = B * V;
    const int NR   = BV * DD;
    const int mask_index = *mask_index_p;

    short* sA   = (short*)&sBuf[w][0];  // row stride 40 shorts (80 B)
    float* sOut = (float*)&sBuf[w][0];  // row stride 36 floats (144 B)

    const int wp0 = (blockIdx.x * NW + w) * PPW;
    const int tr0 = wp0 * DD;

    // ---- descriptor per slot-lane (lanes 32-63 mirror 0-31) ----
    const int sl = lane & (NSL - 1);
    int sr = tr0 + sl;
    if (sr >= NR) sr = NR - 1;
    const int   a_s = adj[sr];
    const float m_s = mask[sr];
    int ac = a_s < 0 ? 0 : (a_s >= V ? V - 1 : a_s);        // JAX clamp
    int bv_s = sr / DD;
    int b_s  = (bv_s >= 2 * V) ? ((bv_s >= 3 * V) ? 3 : 2) : ((bv_s >= V) ? 1 : 0);
    const int gidx = ((b_s * V + ac) << 7) | ((m_s != 0.f) ? 2 : 0)
                   | ((a_s == mask_index) ? 1 : 0);

    // ---- staging: ONE 4-deep batch — 4 bpermute, 8 loads in flight ----
    const char* sb = (const char*)summed;
    int gp[4];
#pragma unroll
    for (int i = 0; i < 4; ++i)
        gp[i] = __builtin_amdgcn_ds_bpermute((8 * i + r8) << 2, gidx);

    f32x4 iv[4], gv[4];
#pragma unroll
    for (int i = 0; i < 4; ++i) {
        int rr = tr0 + 8 * i + r8;
        if (rr >= NR) rr = NR - 1;
        iv[i] = *((const f32x4*)(init + (size_t)rr * FF) + l8);
        gv[i] = *(const f32x4*)(sb + ((uint32_t)gp[i] & ~127u) + (l8 << 4));
    }

#pragma unroll
    for (int i = 0; i < 4; ++i) {
        int slot = 8 * i + r8;               // covers all 32 slots
        f32x4 v = iv[i];
        if (!(gp[i] & 1)) v += gv[i];
        if (gp[i] & 2) v = (f32x4){0.f, 0.f, 0.f, 0.f};
        s16x4 h;
        h[0] = f2bf(v.x); h[1] = f2bf(v.y); h[2] = f2bf(v.z); h[3] = f2bf(v.w);
        *(s16x4*)(sA + slot * 40 + l8 * 4) = h;
    }

    // ---- B-frag (W), bias, a: loaded after staging ----
    bf16x8 bw0, bw1;
#pragma unroll
    for (int j = 0; j < 8; ++j) {
        int k = q * 8 + j;
        bw0[j] = f2bf(Wk[k * FF + col]);
        bw1[j] = f2bf(Wk[k * FF + col + 16]);
    }
    const float bias0 = Wb[col], bias1 = Wb[col + 16];
    const float ak0   = Ak[col], ak1   = Ak[col + 16];

    // ---- A-frags + 4 MFMA (W shared in-register across the wave) ----
    const f32x4 zz = {0.f, 0.f, 0.f, 0.f};
    f32x4 acc0[2], acc1[2];
#pragma unroll
    for (int g4 = 0; g4 < 2; ++g4) {
        bf16x8 af = *(const bf16x8*)(sA + (g4 * 16 + col) * 40 + q * 8);
        acc0[g4] = __builtin_amdgcn_mfma_f32_16x16x32_bf16(af, bw0, zz, 0, 0, 0);
        acc1[g4] = __builtin_amdgcn_mfma_f32_16x16x32_bf16(af, bw1, zz, 0, 0, 0);
    }

    // ---- epilogue: relu/bias/zm, attn dot, aw -> sAW inline ----
#pragma unroll
    for (int g4 = 0; g4 < 2; ++g4) {
#pragma unroll
        for (int reg = 0; reg < 4; ++reg) {
            const int row = g4 * 16 + q * 4 + reg;
            const int fl  = __builtin_amdgcn_ds_bpermute(row << 2, gidx);
            const float zm = (fl & 2) ? 0.f : 1.f;
            float t0 = fmaxf(acc0[g4][reg] + bias0, 0.f) * zm;
            float t1 = fmaxf(acc1[g4][reg] + bias1, 0.f) * zm;
            acc0[g4][reg] = t0;
            acc1[g4][reg] = t1;
            float p = fmaf(t0, ak0, t1 * ak1);
            p = dpp_ror_add(p, 1);
            p = dpp_ror_add(p, 2);
            p = dpp_ror_add(p, 4);
            p = dpp_ror_add(p, 8);           // all 16 lanes hold the row sum
            const float aw = p - 1e7f * (1.f - zm);
            if ((lane & 15) == reg)          // one writer per 16-group
                sAW[w][row] = aw;
        }
    }

    // ---- softmax over the pair's 10 rows ----
    int p_raw = sl / DD;                     // 0..3 (slots 30,31 -> 3)
    const int pe = (p_raw < PPW) ? p_raw : (PPW - 1);
    const int base = pe * DD;
    float mx = -INFINITY;
    float av[DD];
#pragma unroll
    for (int d = 0; d < DD; ++d) { av[d] = sAW[w][base + d]; mx = fmaxf(mx, av[d]); }
    float den = 0.f;
#pragma unroll
    for (int d = 0; d < DD; ++d) den += __expf(av[d] - mx);
    const float coef = __expf(sAW[w][sl] - mx) / den;     // this slot's coefficient

    // ---- coef*T -> sOut (aliases sA; ordering via acc register dependence) ----
#pragma unroll
    for (int g4 = 0; g4 < 2; ++g4) {
#pragma unroll
        for (int reg = 0; reg < 4; ++reg) {
            const int row = g4 * 16 + q * 4 + reg;
            const float cr = __int_as_float(
                __builtin_amdgcn_ds_bpermute(row << 2, __float_as_int(coef)));
            float* op = sOut + row * OSTR + col;
            op[0]  = cr * acc0[g4][reg];
            op[16] = cr * acc1[g4][reg];     // -> ds_write2_b32
        }
    }

    // ---- coalesced epilogue: plain b128 stores (L2 absorbs) ----
    int nrows = NR - tr0;
    if (nrows < 0) nrows = 0;
    if (nrows > RPW) nrows = RPW;
    const int lim4 = nrows * 8;              // <= 240
    f32x4* ob = (f32x4*)(out + (size_t)tr0 * FF);
#pragma unroll
    for (int k = 0; k < 4; ++k) {
        int m = lane + (k << 6);
        if (m < lim4) {
            const f32x4 v = *(const f32x4*)(sOut + (m >> 3) * OSTR + ((m & 7) << 2));
            ob[m] = v;
        }
    }
}

extern "C" void kernel_launch(void* const* d_in, const int* in_sizes, int n_in,
                              void* d_out, int out_size, void* d_ws, size_t ws_size,
                              hipStream_t stream) {
    const float* inputs = (const float*)d_in[0];
    const float* init   = (const float*)d_in[1];
    const float* mask   = (const float*)d_in[2];
    const float* Wk     = (const float*)d_in[3];
    const float* Wb     = (const float*)d_in[4];
    const float* Ak     = (const float*)d_in[5];
    const int*   adj    = (const int*)d_in[6];
    const int*   mip    = (const int*)d_in[7];

    const int B   = 4;
    const int BVD = in_sizes[2];          // B*V*D
    const int V   = BVD / (B * DD);
    const int BV  = B * V;

    float* summed = (float*)d_ws;         // B*V*FF floats = 10.24 MB
    int n4 = BV * (FF / 4);
    hipLaunchKernelGGL(sum_d4_kernel, dim3((n4 + 255) / 256), dim3(256), 0, stream,
                       (const f32x4*)inputs, (f32x4*)summed, n4);
    const int ppb = NW * PPW;             // 12 pairs per block
    hipLaunchKernelGGL(gat_kernel, dim3((BV + ppb - 1) / ppb), dim3(NT), 0, stream,
                       summed, init, mask, Wk, Wb, Ak, adj, mip, (float*)d_out, B, V);
}

// Round 25
// 58.733 us; speedup vs baseline: 1.1265x; 1.0951x over previous
//
#include <hip/hip_runtime.h>
#include <hip/hip_bf16.h>
#include <cmath>

#define DD   10
#define FF   32
#define PPW  3                  // pairs per wave (30 rows + 2 shadow slots)
#define NSL  32                 // slots per wave (2 MFMA row-groups)
#define NW   4                  // waves per block
#define NT   (NW * 64)
#define RPW  (PPW * DD)         // 30 real rows per wave
#define OSTR 36                 // out LDS row stride in floats (144 B)

typedef float f32x4  __attribute__((ext_vector_type(4)));
typedef short bf16x8 __attribute__((ext_vector_type(8)));
typedef short s16x4  __attribute__((ext_vector_type(4)));

__device__ __forceinline__ short f2bf(float x) {
    __hip_bfloat16 h = __float2bfloat16(x);
    return *reinterpret_cast<short*>(&h);
}
__device__ __forceinline__ float bf2f(short s) {
    return __int_as_float(((int)(unsigned short)s) << 16);
}

// Kernel 1: summed[b,v,f] = sum_d inputs[b,v,d,f], stored as bf16 (half bytes)
__global__ __launch_bounds__(256) void sum_d4_kernel(
    const f32x4* __restrict__ in, s16x4* __restrict__ out, int n4) {
    int idx = blockIdx.x * 256 + threadIdx.x;
    if (idx >= n4) return;
    int f4 = idx & 7;
    int bv = idx >> 3;
    const f32x4* p = in + (size_t)bv * (DD * 8) + f4;
    f32x4 s = __builtin_nontemporal_load(p);
#pragma unroll
    for (int d = 1; d < DD; ++d) s += __builtin_nontemporal_load(p + d * 8);
    s16x4 h;
    h[0] = f2bf(s.x); h[1] = f2bf(s.y); h[2] = f2bf(s.z); h[3] = f2bf(s.w);
    out[idx] = h;                        // coalesced 8 B/lane
}

__device__ __forceinline__ float dpp_ror_add(float v, const int sel) {
    int x;
    switch (sel) {
        case 1:  x = __builtin_amdgcn_update_dpp(0, __float_as_int(v), 0x121, 0xF, 0xF, true); break;
        case 2:  x = __builtin_amdgcn_update_dpp(0, __float_as_int(v), 0x122, 0xF, 0xF, true); break;
        case 4:  x = __builtin_amdgcn_update_dpp(0, __float_as_int(v), 0x124, 0xF, 0xF, true); break;
        default: x = __builtin_amdgcn_update_dpp(0, __float_as_int(v), 0x128, 0xF, 0xF, true); break;
    }
    return v + __int_as_float(x);
}

// Kernel 2 (R24 structure, bf16 gather table): 64 B gather rows (L2-resident),
//   b64 gather loads -> bf16 A -> 4 MFMA -> inline aw -> softmax ->
//   LDS out-buffer -> coalesced plain b128 stores.
__global__ __launch_bounds__(NT) void gat_kernel(
    const short* __restrict__ summed,    // bf16
    const float* __restrict__ init,
    const float* __restrict__ mask,
    const float* __restrict__ Wk,
    const float* __restrict__ Wb,
    const float* __restrict__ Ak,
    const int* __restrict__ adj,
    const int* __restrict__ mask_index_p,
    float* __restrict__ out,
    int B, int V) {
    // sA (32 x 40 shorts) and sOut (32 x 36 floats) alias; ordering via acc dep.
    __shared__ __align__(16) char sBuf[NW][NSL * OSTR * 4];   // 18432 B
    __shared__ float sAW[NW][NSL];

    const int t    = threadIdx.x;
    const int lane = t & 63;
    const int w    = t >> 6;
    const int l8   = lane & 7;          // chunk within row (staging)
    const int r8   = lane >> 3;         // row within 8-row staging group
    const int col  = lane & 15;         // MFMA col
    const int q    = lane >> 4;         // MFMA k-/row-quadrant
    const int BV   = B * V;
    const int NR   = BV * DD;
    const int mask_index = *mask_index_p;

    short* sA   = (short*)&sBuf[w][0];  // row stride 40 shorts (80 B)
    float* sOut = (float*)&sBuf[w][0];  // row stride 36 floats (144 B)

    const int wp0 = (blockIdx.x * NW + w) * PPW;
    const int tr0 = wp0 * DD;

    // ---- descriptor per slot-lane (lanes 32-63 mirror 0-31) ----
    const int sl = lane & (NSL - 1);
    int sr = tr0 + sl;
    if (sr >= NR) sr = NR - 1;
    const int   a_s = adj[sr];
    const float m_s = mask[sr];
    int ac = a_s < 0 ? 0 : (a_s >= V ? V - 1 : a_s);        // JAX clamp
    int bv_s = sr / DD;
    int b_s  = (bv_s >= 2 * V) ? ((bv_s >= 3 * V) ? 3 : 2) : ((bv_s >= V) ? 1 : 0);
    // bf16 rows: 64 B -> byte offset = idx << 6; low 2 bits carry flags
    const int gidx = ((b_s * V + ac) << 6) | ((m_s != 0.f) ? 2 : 0)
                   | ((a_s == mask_index) ? 1 : 0);

    // ---- staging: 4 bpermute, 8 loads (4 init b128 + 4 gather b64) in flight ----
    const char* sb = (const char*)summed;
    int gp[4];
#pragma unroll
    for (int i = 0; i < 4; ++i)
        gp[i] = __builtin_amdgcn_ds_bpermute((8 * i + r8) << 2, gidx);

    f32x4 iv[4];
    s16x4 gh[4];
#pragma unroll
    for (int i = 0; i < 4; ++i) {
        int rr = tr0 + 8 * i + r8;
        if (rr >= NR) rr = NR - 1;
        iv[i] = *((const f32x4*)(init + (size_t)rr * FF) + l8);
        gh[i] = *(const s16x4*)(sb + ((uint32_t)gp[i] & ~63u) + (l8 << 3));
    }

#pragma unroll
    for (int i = 0; i < 4; ++i) {
        int slot = 8 * i + r8;               // covers all 32 slots
        f32x4 v = iv[i];
        if (!(gp[i] & 1)) {                  // neighbor != mask_index
            f32x4 g32;
            g32.x = bf2f(gh[i][0]); g32.y = bf2f(gh[i][1]);
            g32.z = bf2f(gh[i][2]); g32.w = bf2f(gh[i][3]);
            v += g32;
        }
        if (gp[i] & 2) v = (f32x4){0.f, 0.f, 0.f, 0.f};
        s16x4 h;
        h[0] = f2bf(v.x); h[1] = f2bf(v.y); h[2] = f2bf(v.z); h[3] = f2bf(v.w);
        *(s16x4*)(sA + slot * 40 + l8 * 4) = h;
    }

    // ---- B-frag (W), bias, a: loaded after staging ----
    bf16x8 bw0, bw1;
#pragma unroll
    for (int j = 0; j < 8; ++j) {
        int k = q * 8 + j;
        bw0[j] = f2bf(Wk[k * FF + col]);
        bw1[j] = f2bf(Wk[k * FF + col + 16]);
    }
    const float bias0 = Wb[col], bias1 = Wb[col + 16];
    const float ak0   = Ak[col], ak1   = Ak[col + 16];

    // ---- A-frags + 4 MFMA (W shared in-register across the wave) ----
    const f32x4 zz = {0.f, 0.f, 0.f, 0.f};
    f32x4 acc0[2], acc1[2];
#pragma unroll
    for (int g4 = 0; g4 < 2; ++g4) {
        bf16x8 af = *(const bf16x8*)(sA + (g4 * 16 + col) * 40 + q * 8);
        acc0[g4] = __builtin_amdgcn_mfma_f32_16x16x32_bf16(af, bw0, zz, 0, 0, 0);
        acc1[g4] = __builtin_amdgcn_mfma_f32_16x16x32_bf16(af, bw1, zz, 0, 0, 0);
    }

    // ---- epilogue: relu/bias/zm, attn dot, aw -> sAW inline ----
#pragma unroll
    for (int g4 = 0; g4 < 2; ++g4) {
#pragma unroll
        for (int reg = 0; reg < 4; ++reg) {
            const int row = g4 * 16 + q * 4 + reg;
            const int fl  = __builtin_amdgcn_ds_bpermute(row << 2, gidx);
            const float zm = (fl & 2) ? 0.f : 1.f;
            float t0 = fmaxf(acc0[g4][reg] + bias0, 0.f) * zm;
            float t1 = fmaxf(acc1[g4][reg] + bias1, 0.f) * zm;
            acc0[g4][reg] = t0;
            acc1[g4][reg] = t1;
            float p = fmaf(t0, ak0, t1 * ak1);
            p = dpp_ror_add(p, 1);
            p = dpp_ror_add(p, 2);
            p = dpp_ror_add(p, 4);
            p = dpp_ror_add(p, 8);           // all 16 lanes hold the row sum
            const float aw = p - 1e7f * (1.f - zm);
            if ((lane & 15) == reg)          // one writer per 16-group
                sAW[w][row] = aw;
        }
    }

    // ---- softmax over the pair's 10 rows ----
    int p_raw = sl / DD;                     // 0..3 (slots 30,31 -> 3)
    const int pe = (p_raw < PPW) ? p_raw : (PPW - 1);
    const int base = pe * DD;
    float mx = -INFINITY;
    float av[DD];
#pragma unroll
    for (int d = 0; d < DD; ++d) { av[d] = sAW[w][base + d]; mx = fmaxf(mx, av[d]); }
    float den = 0.f;
#pragma unroll
    for (int d = 0; d < DD; ++d) den += __expf(av[d] - mx);
    const float coef = __expf(sAW[w][sl] - mx) / den;     // this slot's coefficient

    // ---- coef*T -> sOut (aliases sA; ordering via acc register dependence) ----
#pragma unroll
    for (int g4 = 0; g4 < 2; ++g4) {
#pragma unroll
        for (int reg = 0; reg < 4; ++reg) {
            const int row = g4 * 16 + q * 4 + reg;
            const float cr = __int_as_float(
                __builtin_amdgcn_ds_bpermute(row << 2, __float_as_int(coef)));
            float* op = sOut + row * OSTR + col;
            op[0]  = cr * acc0[g4][reg];
            op[16] = cr * acc1[g4][reg];     // -> ds_write2_b32
        }
    }

    // ---- coalesced epilogue: plain b128 stores (L2 absorbs) ----
    int nrows = NR - tr0;
    if (nrows < 0) nrows = 0;
    if (nrows > RPW) nrows = RPW;
    const int lim4 = nrows * 8;              // <= 240
    f32x4* ob = (f32x4*)(out + (size_t)tr0 * FF);
#pragma unroll
    for (int k = 0; k < 4; ++k) {
        int m = lane + (k << 6);
        if (m < lim4) {
            const f32x4 v = *(const f32x4*)(sOut + (m >> 3) * OSTR + ((m & 7) << 2));
            ob[m] = v;
        }
    }
}

extern "C" void kernel_launch(void* const* d_in, const int* in_sizes, int n_in,
                              void* d_out, int out_size, void* d_ws, size_t ws_size,
                              hipStream_t stream) {
    const float* inputs = (const float*)d_in[0];
    const float* init   = (const float*)d_in[1];
    const float* mask   = (const float*)d_in[2];
    const float* Wk     = (const float*)d_in[3];
    const float* Wb     = (const float*)d_in[4];
    const float* Ak     = (const float*)d_in[5];
    const int*   adj    = (const int*)d_in[6];
    const int*   mip    = (const int*)d_in[7];

    const int B   = 4;
    const int BVD = in_sizes[2];          // B*V*D
    const int V   = BVD / (B * DD);
    const int BV  = B * V;

    short* summed = (short*)d_ws;         // B*V*FF bf16 = 5.12 MB
    int n4 = BV * (FF / 4);
    hipLaunchKernelGGL(sum_d4_kernel, dim3((n4 + 255) / 256), dim3(256), 0, stream,
                       (const f32x4*)inputs, (s16x4*)summed, n4);
    const int ppb = NW * PPW;             // 12 pairs per block
    hipLaunchKernelGGL(gat_kernel, dim3((BV + ppb - 1) / ppb), dim3(NT), 0, stream,
                       summed, init, mask, Wk, Wb, Ak, adj, mip, (float*)d_out, B, V);
}

// Round 26
// 51.798 us; speedup vs baseline: 1.2773x; 1.1339x over previous
//
#include <hip/hip_runtime.h>
#include <hip/hip_bf16.h>
#include <cmath>

#define DD   10
#define FF   32
#define PPW  3                  // pairs per wave (30 rows + 2 shadow slots)
#define NSL  32                 // slots per wave (2 MFMA row-groups)
#define NW   4                  // waves per block
#define NT   (NW * 64)
#define RPW  (PPW * DD)         // 30 real rows per wave
#define OSTR 36                 // out LDS row stride in floats (144 B)

typedef float f32x4  __attribute__((ext_vector_type(4)));
typedef short bf16x8 __attribute__((ext_vector_type(8)));
typedef short s16x4  __attribute__((ext_vector_type(4)));

__device__ __forceinline__ short f2bf(float x) {
    __hip_bfloat16 h = __float2bfloat16(x);
    return *reinterpret_cast<short*>(&h);
}
__device__ __forceinline__ float bf2f(short s) {
    return __int_as_float(((int)(unsigned short)s) << 16);
}

// Kernel 1: summed[b,v,f] = sum_d inputs[b,v,d,f], stored as bf16 (half bytes)
__global__ __launch_bounds__(256) void sum_d4_kernel(
    const f32x4* __restrict__ in, s16x4* __restrict__ out, int n4) {
    int idx = blockIdx.x * 256 + threadIdx.x;
    if (idx >= n4) return;
    int f4 = idx & 7;
    int bv = idx >> 3;
    const f32x4* p = in + (size_t)bv * (DD * 8) + f4;
    f32x4 s = __builtin_nontemporal_load(p);
#pragma unroll
    for (int d = 1; d < DD; ++d) s += __builtin_nontemporal_load(p + d * 8);
    s16x4 h;
    h[0] = f2bf(s.x); h[1] = f2bf(s.y); h[2] = f2bf(s.z); h[3] = f2bf(s.w);
    out[idx] = h;                        // coalesced 8 B/lane
}

__device__ __forceinline__ float dpp_ror_add(float v, const int sel) {
    int x;
    switch (sel) {
        case 1:  x = __builtin_amdgcn_update_dpp(0, __float_as_int(v), 0x121, 0xF, 0xF, true); break;
        case 2:  x = __builtin_amdgcn_update_dpp(0, __float_as_int(v), 0x122, 0xF, 0xF, true); break;
        case 4:  x = __builtin_amdgcn_update_dpp(0, __float_as_int(v), 0x124, 0xF, 0xF, true); break;
        default: x = __builtin_amdgcn_update_dpp(0, __float_as_int(v), 0x128, 0xF, 0xF, true); break;
    }
    return v + __int_as_float(x);
}

// Kernel 2 (R25 + dead-load redirection): rows with zm==0 discard their init
//   and gather values, so their load ADDRESSES are cndmask'd to one hot line
//   (unconditional loads keep MLP; ~50% of init HBM fetch vanishes).
__global__ __launch_bounds__(NT) void gat_kernel(
    const short* __restrict__ summed,    // bf16
    const float* __restrict__ init,
    const float* __restrict__ mask,
    const float* __restrict__ Wk,
    const float* __restrict__ Wb,
    const float* __restrict__ Ak,
    const int* __restrict__ adj,
    const int* __restrict__ mask_index_p,
    float* __restrict__ out,
    int B, int V) {
    // sA (32 x 40 shorts) and sOut (32 x 36 floats) alias; ordering via acc dep.
    __shared__ __align__(16) char sBuf[NW][NSL * OSTR * 4];   // 18432 B
    __shared__ float sAW[NW][NSL];

    const int t    = threadIdx.x;
    const int lane = t & 63;
    const int w    = t >> 6;
    const int l8   = lane & 7;          // chunk within row (staging)
    const int r8   = lane >> 3;         // row within 8-row staging group
    const int col  = lane & 15;         // MFMA col
    const int q    = lane >> 4;         // MFMA k-/row-quadrant
    const int BV   = B * V;
    const int NR   = BV * DD;
    const int mask_index = *mask_index_p;

    short* sA   = (short*)&sBuf[w][0];  // row stride 40 shorts (80 B)
    float* sOut = (float*)&sBuf[w][0];  // row stride 36 floats (144 B)

    const int wp0 = (blockIdx.x * NW + w) * PPW;
    const int tr0 = wp0 * DD;

    // ---- descriptor per slot-lane (lanes 32-63 mirror 0-31) ----
    const int sl = lane & (NSL - 1);
    int sr = tr0 + sl;
    if (sr >= NR) sr = NR - 1;
    const int   a_s = adj[sr];
    const float m_s = mask[sr];
    int ac = a_s < 0 ? 0 : (a_s >= V ? V - 1 : a_s);        // JAX clamp
    int bv_s = sr / DD;
    int b_s  = (bv_s >= 2 * V) ? ((bv_s >= 3 * V) ? 3 : 2) : ((bv_s >= V) ? 1 : 0);
    // bf16 rows: 64 B -> byte offset = idx << 6; low 2 bits carry flags
    const int gidx = ((b_s * V + ac) << 6) | ((m_s != 0.f) ? 2 : 0)
                   | ((a_s == mask_index) ? 1 : 0);

    // ---- staging: 4 bpermute, 8 loads in flight; dead rows -> hot line ----
    const char* sb = (const char*)summed;
    int gp[4];
#pragma unroll
    for (int i = 0; i < 4; ++i)
        gp[i] = __builtin_amdgcn_ds_bpermute((8 * i + r8) << 2, gidx);

    f32x4 iv[4];
    s16x4 gh[4];
#pragma unroll
    for (int i = 0; i < 4; ++i) {
        int rr = tr0 + 8 * i + r8;
        if (rr >= NR) rr = NR - 1;
        const bool dead = (gp[i] & 2) != 0;     // zm==0: value will be zeroed
        size_t ioff = dead ? 0 : ((size_t)rr * FF + (l8 << 2));
        iv[i] = *(const f32x4*)(init + ioff);   // dead rows hit init[0..] (L2-hot)
        uint32_t goff = dead ? 0u : (((uint32_t)gp[i] & ~63u) + (l8 << 3));
        gh[i] = *(const s16x4*)(sb + goff);     // dead rows hit summed[0..]
    }

#pragma unroll
    for (int i = 0; i < 4; ++i) {
        int slot = 8 * i + r8;               // covers all 32 slots
        f32x4 v = iv[i];
        if (!(gp[i] & 1)) {                  // neighbor != mask_index
            f32x4 g32;
            g32.x = bf2f(gh[i][0]); g32.y = bf2f(gh[i][1]);
            g32.z = bf2f(gh[i][2]); g32.w = bf2f(gh[i][3]);
            v += g32;
        }
        if (gp[i] & 2) v = (f32x4){0.f, 0.f, 0.f, 0.f};
        s16x4 h;
        h[0] = f2bf(v.x); h[1] = f2bf(v.y); h[2] = f2bf(v.z); h[3] = f2bf(v.w);
        *(s16x4*)(sA + slot * 40 + l8 * 4) = h;
    }

    // ---- B-frag (W), bias, a: loaded after staging ----
    bf16x8 bw0, bw1;
#pragma unroll
    for (int j = 0; j < 8; ++j) {
        int k = q * 8 + j;
        bw0[j] = f2bf(Wk[k * FF + col]);
        bw1[j] = f2bf(Wk[k * FF + col + 16]);
    }
    const float bias0 = Wb[col], bias1 = Wb[col + 16];
    const float ak0   = Ak[col], ak1   = Ak[col + 16];

    // ---- A-frags + 4 MFMA (W shared in-register across the wave) ----
    const f32x4 zz = {0.f, 0.f, 0.f, 0.f};
    f32x4 acc0[2], acc1[2];
#pragma unroll
    for (int g4 = 0; g4 < 2; ++g4) {
        bf16x8 af = *(const bf16x8*)(sA + (g4 * 16 + col) * 40 + q * 8);
        acc0[g4] = __builtin_amdgcn_mfma_f32_16x16x32_bf16(af, bw0, zz, 0, 0, 0);
        acc1[g4] = __builtin_amdgcn_mfma_f32_16x16x32_bf16(af, bw1, zz, 0, 0, 0);
    }

    // ---- epilogue: relu/bias/zm, attn dot, aw -> sAW inline ----
#pragma unroll
    for (int g4 = 0; g4 < 2; ++g4) {
#pragma unroll
        for (int reg = 0; reg < 4; ++reg) {
            const int row = g4 * 16 + q * 4 + reg;
            const int fl  = __builtin_amdgcn_ds_bpermute(row << 2, gidx);
            const float zm = (fl & 2) ? 0.f : 1.f;
            float t0 = fmaxf(acc0[g4][reg] + bias0, 0.f) * zm;
            float t1 = fmaxf(acc1[g4][reg] + bias1, 0.f) * zm;
            acc0[g4][reg] = t0;
            acc1[g4][reg] = t1;
            float p = fmaf(t0, ak0, t1 * ak1);
            p = dpp_ror_add(p, 1);
            p = dpp_ror_add(p, 2);
            p = dpp_ror_add(p, 4);
            p = dpp_ror_add(p, 8);           // all 16 lanes hold the row sum
            const float aw = p - 1e7f * (1.f - zm);
            if ((lane & 15) == reg)          // one writer per 16-group
                sAW[w][row] = aw;
        }
    }

    // ---- softmax over the pair's 10 rows ----
    int p_raw = sl / DD;                     // 0..3 (slots 30,31 -> 3)
    const int pe = (p_raw < PPW) ? p_raw : (PPW - 1);
    const int base = pe * DD;
    float mx = -INFINITY;
    float av[DD];
#pragma unroll
    for (int d = 0; d < DD; ++d) { av[d] = sAW[w][base + d]; mx = fmaxf(mx, av[d]); }
    float den = 0.f;
#pragma unroll
    for (int d = 0; d < DD; ++d) den += __expf(av[d] - mx);
    const float coef = __expf(sAW[w][sl] - mx) / den;     // this slot's coefficient

    // ---- coef*T -> sOut (aliases sA; ordering via acc register dependence) ----
#pragma unroll
    for (int g4 = 0; g4 < 2; ++g4) {
#pragma unroll
        for (int reg = 0; reg < 4; ++reg) {
            const int row = g4 * 16 + q * 4 + reg;
            const float cr = __int_as_float(
                __builtin_amdgcn_ds_bpermute(row << 2, __float_as_int(coef)));
            float* op = sOut + row * OSTR + col;
            op[0]  = cr * acc0[g4][reg];
            op[16] = cr * acc1[g4][reg];     // -> ds_write2_b32
        }
    }

    // ---- coalesced epilogue: plain b128 stores (L2 absorbs) ----
    int nrows = NR - tr0;
    if (nrows < 0) nrows = 0;
    if (nrows > RPW) nrows = RPW;
    const int lim4 = nrows * 8;              // <= 240
    f32x4* ob = (f32x4*)(out + (size_t)tr0 * FF);
#pragma unroll
    for (int k = 0; k < 4; ++k) {
        int m = lane + (k << 6);
        if (m < lim4) {
            const f32x4 v = *(const f32x4*)(sOut + (m >> 3) * OSTR + ((m & 7) << 2));
            ob[m] = v;
        }
    }
}

extern "C" void kernel_launch(void* const* d_in, const int* in_sizes, int n_in,
                              void* d_out, int out_size, void* d_ws, size_t ws_size,
                              hipStream_t stream) {
    const float* inputs = (const float*)d_in[0];
    const float* init   = (const float*)d_in[1];
    const float* mask   = (const float*)d_in[2];
    const float* Wk     = (const float*)d_in[3];
    const float* Wb     = (const float*)d_in[4];
    const float* Ak     = (const float*)d_in[5];
    const int*   adj    = (const int*)d_in[6];
    const int*   mip    = (const int*)d_in[7];

    const int B   = 4;
    const int BVD = in_sizes[2];          // B*V*D
    const int V   = BVD / (B * DD);
    const int BV  = B * V;

    short* summed = (short*)d_ws;         // B*V*FF bf16 = 5.12 MB
    int n4 = BV * (FF / 4);
    hipLaunchKernelGGL(sum_d4_kernel, dim3((n4 + 255) / 256), dim3(256), 0, stream,
                       (const f32x4*)inputs, (s16x4*)summed, n4);
    const int ppb = NW * PPW;             // 12 pairs per block
    hipLaunchKernelGGL(gat_kernel, dim3((BV + ppb - 1) / ppb), dim3(NT), 0, stream,
                       summed, init, mask, Wk, Wb, Ak, adj, mip, (float*)d_out, B, V);
}

// Round 27
// 50.650 us; speedup vs baseline: 1.3063x; 1.0227x over previous
//
#include <hip/hip_runtime.h>
#include <hip/hip_bf16.h>
#include <cmath>

#define DD   10
#define FF   32
#define PPW  3                  // pairs per wave (30 rows + 2 shadow slots)
#define NSL  32                 // slots per wave (2 MFMA row-groups)
#define NW   4                  // waves per block
#define NT   (NW * 64)
#define RPW  (PPW * DD)         // 30 real rows per wave
#define OSTR 36                 // out LDS row stride in floats (144 B)
#define NXCD 8

typedef float f32x4  __attribute__((ext_vector_type(4)));
typedef short bf16x8 __attribute__((ext_vector_type(8)));
typedef short s16x4  __attribute__((ext_vector_type(4)));

__device__ __forceinline__ short f2bf(float x) {
    __hip_bfloat16 h = __float2bfloat16(x);
    return *reinterpret_cast<short*>(&h);
}
__device__ __forceinline__ float bf2f(short s) {
    return __int_as_float(((int)(unsigned short)s) << 16);
}

// Kernel 1: summed[b,v,f] = sum_d inputs[b,v,d,f], stored as bf16 (half bytes)
__global__ __launch_bounds__(256) void sum_d4_kernel(
    const f32x4* __restrict__ in, s16x4* __restrict__ out, int n4) {
    int idx = blockIdx.x * 256 + threadIdx.x;
    if (idx >= n4) return;
    int f4 = idx & 7;
    int bv = idx >> 3;
    const f32x4* p = in + (size_t)bv * (DD * 8) + f4;
    f32x4 s = __builtin_nontemporal_load(p);
#pragma unroll
    for (int d = 1; d < DD; ++d) s += __builtin_nontemporal_load(p + d * 8);
    s16x4 h;
    h[0] = f2bf(s.x); h[1] = f2bf(s.y); h[2] = f2bf(s.z); h[3] = f2bf(s.w);
    out[idx] = h;                        // coalesced 8 B/lane
}

__device__ __forceinline__ float dpp_ror_add(float v, const int sel) {
    int x;
    switch (sel) {
        case 1:  x = __builtin_amdgcn_update_dpp(0, __float_as_int(v), 0x121, 0xF, 0xF, true); break;
        case 2:  x = __builtin_amdgcn_update_dpp(0, __float_as_int(v), 0x122, 0xF, 0xF, true); break;
        case 4:  x = __builtin_amdgcn_update_dpp(0, __float_as_int(v), 0x124, 0xF, 0xF, true); break;
        default: x = __builtin_amdgcn_update_dpp(0, __float_as_int(v), 0x128, 0xF, 0xF, true); break;
    }
    return v + __int_as_float(x);
}

// Kernel 2 (R26 + bijective XCD swizzle): contiguous bv-chunks per XCD keep
//   each XCD's gather table slice L2-resident.
__global__ __launch_bounds__(NT) void gat_kernel(
    const short* __restrict__ summed,    // bf16
    const float* __restrict__ init,
    const float* __restrict__ mask,
    const float* __restrict__ Wk,
    const float* __restrict__ Wb,
    const float* __restrict__ Ak,
    const int* __restrict__ adj,
    const int* __restrict__ mask_index_p,
    float* __restrict__ out,
    int B, int V) {
    // sA (32 x 40 shorts) and sOut (32 x 36 floats) alias; ordering via acc dep.
    __shared__ __align__(16) char sBuf[NW][NSL * OSTR * 4];   // 18432 B
    __shared__ float sAW[NW][NSL];

    // ---- bijective XCD-chunked block swizzle (m204 variant) ----
    const int nwg  = gridDim.x;
    const int bid  = blockIdx.x;
    const int xcd  = bid & (NXCD - 1);
    const int rest = bid >> 3;
    const int qd   = nwg >> 3, rm = nwg & (NXCD - 1);
    const int swz  = (xcd < rm ? xcd * (qd + 1) : rm * (qd + 1) + (xcd - rm) * qd) + rest;

    const int t    = threadIdx.x;
    const int lane = t & 63;
    const int w    = t >> 6;
    const int l8   = lane & 7;          // chunk within row (staging)
    const int r8   = lane >> 3;         // row within 8-row staging group
    const int col  = lane & 15;         // MFMA col
    const int q    = lane >> 4;         // MFMA k-/row-quadrant
    const int BV   = B * V;
    const int NR   = BV * DD;
    const int mask_index = *mask_index_p;

    short* sA   = (short*)&sBuf[w][0];  // row stride 40 shorts (80 B)
    float* sOut = (float*)&sBuf[w][0];  // row stride 36 floats (144 B)

    const int wp0 = (swz * NW + w) * PPW;
    const int tr0 = wp0 * DD;

    // ---- descriptor per slot-lane (lanes 32-63 mirror 0-31) ----
    const int sl = lane & (NSL - 1);
    int sr = tr0 + sl;
    if (sr >= NR) sr = NR - 1;
    const int   a_s = adj[sr];
    const float m_s = mask[sr];
    int ac = a_s < 0 ? 0 : (a_s >= V ? V - 1 : a_s);        // JAX clamp
    int bv_s = sr / DD;
    int b_s  = (bv_s >= 2 * V) ? ((bv_s >= 3 * V) ? 3 : 2) : ((bv_s >= V) ? 1 : 0);
    // bf16 rows: 64 B -> byte offset = idx << 6; low 2 bits carry flags
    const int gidx = ((b_s * V + ac) << 6) | ((m_s != 0.f) ? 2 : 0)
                   | ((a_s == mask_index) ? 1 : 0);

    // ---- staging: 4 bpermute, 8 loads in flight; dead rows -> hot line ----
    const char* sb = (const char*)summed;
    int gp[4];
#pragma unroll
    for (int i = 0; i < 4; ++i)
        gp[i] = __builtin_amdgcn_ds_bpermute((8 * i + r8) << 2, gidx);

    f32x4 iv[4];
    s16x4 gh[4];
#pragma unroll
    for (int i = 0; i < 4; ++i) {
        int rr = tr0 + 8 * i + r8;
        if (rr >= NR) rr = NR - 1;
        const bool dead = (gp[i] & 2) != 0;     // zm==0: value will be zeroed
        size_t ioff = dead ? 0 : ((size_t)rr * FF + (l8 << 2));
        iv[i] = *(const f32x4*)(init + ioff);   // dead rows hit init[0..] (L2-hot)
        uint32_t goff = dead ? 0u : (((uint32_t)gp[i] & ~63u) + (l8 << 3));
        gh[i] = *(const s16x4*)(sb + goff);     // dead rows hit summed[0..]
    }

#pragma unroll
    for (int i = 0; i < 4; ++i) {
        int slot = 8 * i + r8;               // covers all 32 slots
        f32x4 v = iv[i];
        if (!(gp[i] & 1)) {                  // neighbor != mask_index
            f32x4 g32;
            g32.x = bf2f(gh[i][0]); g32.y = bf2f(gh[i][1]);
            g32.z = bf2f(gh[i][2]); g32.w = bf2f(gh[i][3]);
            v += g32;
        }
        if (gp[i] & 2) v = (f32x4){0.f, 0.f, 0.f, 0.f};
        s16x4 h;
        h[0] = f2bf(v.x); h[1] = f2bf(v.y); h[2] = f2bf(v.z); h[3] = f2bf(v.w);
        *(s16x4*)(sA + slot * 40 + l8 * 4) = h;
    }

    // ---- B-frag (W), bias, a: loaded after staging ----
    bf16x8 bw0, bw1;
#pragma unroll
    for (int j = 0; j < 8; ++j) {
        int k = q * 8 + j;
        bw0[j] = f2bf(Wk[k * FF + col]);
        bw1[j] = f2bf(Wk[k * FF + col + 16]);
    }
    const float bias0 = Wb[col], bias1 = Wb[col + 16];
    const float ak0   = Ak[col], ak1   = Ak[col + 16];

    // ---- A-frags + 4 MFMA (W shared in-register across the wave) ----
    const f32x4 zz = {0.f, 0.f, 0.f, 0.f};
    f32x4 acc0[2], acc1[2];
#pragma unroll
    for (int g4 = 0; g4 < 2; ++g4) {
        bf16x8 af = *(const bf16x8*)(sA + (g4 * 16 + col) * 40 + q * 8);
        acc0[g4] = __builtin_amdgcn_mfma_f32_16x16x32_bf16(af, bw0, zz, 0, 0, 0);
        acc1[g4] = __builtin_amdgcn_mfma_f32_16x16x32_bf16(af, bw1, zz, 0, 0, 0);
    }

    // ---- epilogue: relu/bias/zm, attn dot, aw -> sAW inline ----
#pragma unroll
    for (int g4 = 0; g4 < 2; ++g4) {
#pragma unroll
        for (int reg = 0; reg < 4; ++reg) {
            const int row = g4 * 16 + q * 4 + reg;
            const int fl  = __builtin_amdgcn_ds_bpermute(row << 2, gidx);
            const float zm = (fl & 2) ? 0.f : 1.f;
            float t0 = fmaxf(acc0[g4][reg] + bias0, 0.f) * zm;
            float t1 = fmaxf(acc1[g4][reg] + bias1, 0.f) * zm;
            acc0[g4][reg] = t0;
            acc1[g4][reg] = t1;
            float p = fmaf(t0, ak0, t1 * ak1);
            p = dpp_ror_add(p, 1);
            p = dpp_ror_add(p, 2);
            p = dpp_ror_add(p, 4);
            p = dpp_ror_add(p, 8);           // all 16 lanes hold the row sum
            const float aw = p - 1e7f * (1.f - zm);
            if ((lane & 15) == reg)          // one writer per 16-group
                sAW[w][row] = aw;
        }
    }

    // ---- softmax over the pair's 10 rows ----
    int p_raw = sl / DD;                     // 0..3 (slots 30,31 -> 3)
    const int pe = (p_raw < PPW) ? p_raw : (PPW - 1);
    const int base = pe * DD;
    float mx = -INFINITY;
    float av[DD];
#pragma unroll
    for (int d = 0; d < DD; ++d) { av[d] = sAW[w][base + d]; mx = fmaxf(mx, av[d]); }
    float den = 0.f;
#pragma unroll
    for (int d = 0; d < DD; ++d) den += __expf(av[d] - mx);
    const float coef = __expf(sAW[w][sl] - mx) / den;     // this slot's coefficient

    // ---- coef*T -> sOut (aliases sA; ordering via acc register dependence) ----
#pragma unroll
    for (int g4 = 0; g4 < 2; ++g4) {
#pragma unroll
        for (int reg = 0; reg < 4; ++reg) {
            const int row = g4 * 16 + q * 4 + reg;
            const float cr = __int_as_float(
                __builtin_amdgcn_ds_bpermute(row << 2, __float_as_int(coef)));
            float* op = sOut + row * OSTR + col;
            op[0]  = cr * acc0[g4][reg];
            op[16] = cr * acc1[g4][reg];     // -> ds_write2_b32
        }
    }

    // ---- coalesced epilogue: plain b128 stores (L2 absorbs) ----
    int nrows = NR - tr0;
    if (nrows < 0) nrows = 0;
    if (nrows > RPW) nrows = RPW;
    const int lim4 = nrows * 8;              // <= 240
    f32x4* ob = (f32x4*)(out + (size_t)tr0 * FF);
#pragma unroll
    for (int k = 0; k < 4; ++k) {
        int m = lane + (k << 6);
        if (m < lim4) {
            const f32x4 v = *(const f32x4*)(sOut + (m >> 3) * OSTR + ((m & 7) << 2));
            ob[m] = v;
        }
    }
}

extern "C" void kernel_launch(void* const* d_in, const int* in_sizes, int n_in,
                              void* d_out, int out_size, void* d_ws, size_t ws_size,
                              hipStream_t stream) {
    const float* inputs = (const float*)d_in[0];
    const float* init   = (const float*)d_in[1];
    const float* mask   = (const float*)d_in[2];
    const float* Wk     = (const float*)d_in[3];
    const float* Wb     = (const float*)d_in[4];
    const float* Ak     = (const float*)d_in[5];
    const int*   adj    = (const int*)d_in[6];
    const int*   mip    = (const int*)d_in[7];

    const int B   = 4;
    const int BVD = in_sizes[2];          // B*V*D
    const int V   = BVD / (B * DD);
    const int BV  = B * V;

    short* summed = (short*)d_ws;         // B*V*FF bf16 = 5.12 MB
    int n4 = BV * (FF / 4);
    hipLaunchKernelGGL(sum_d4_kernel, dim3((n4 + 255) / 256), dim3(256), 0, stream,
                       (const f32x4*)inputs, (s16x4*)summed, n4);
    const int ppb = NW * PPW;             // 12 pairs per block
    hipLaunchKernelGGL(gat_kernel, dim3((BV + ppb - 1) / ppb), dim3(NT), 0, stream,
                       summed, init, mask, Wk, Wb, Ak, adj, mip, (float*)d_out, B, V);
}